// Round 1
// baseline (627.038 us; speedup 1.0000x reference)
//
#include <hip/hip_runtime.h>
#include <math.h>

#define D 5
#define B 2048
#define L 50
#define LS 50
#define DH 128
#define DU 128
#define QK 64
#define CD 64
#define EPS 1e-5f

__device__ __forceinline__ float wsum(float v) {
    v += __shfl_xor(v, 1, 64);
    v += __shfl_xor(v, 2, 64);
    v += __shfl_xor(v, 4, 64);
    v += __shfl_xor(v, 8, 64);
    v += __shfl_xor(v, 16, 64);
    v += __shfl_xor(v, 32, 64);
    return v;
}

__device__ __forceinline__ float wmax(float v) {
    v = fmaxf(v, __shfl_xor(v, 1, 64));
    v = fmaxf(v, __shfl_xor(v, 2, 64));
    v = fmaxf(v, __shfl_xor(v, 4, 64));
    v = fmaxf(v, __shfl_xor(v, 8, 64));
    v = fmaxf(v, __shfl_xor(v, 16, 64));
    v = fmaxf(v, __shfl_xor(v, 32, 64));
    return v;
}

// reduction across a 32-lane group (xor bits 0..4 keep bit5 invariant)
__device__ __forceinline__ float gsum32(float v) {
    v += __shfl_xor(v, 1, 64);
    v += __shfl_xor(v, 2, 64);
    v += __shfl_xor(v, 4, 64);
    v += __shfl_xor(v, 8, 64);
    v += __shfl_xor(v, 16, 64);
    return v;
}

__device__ __forceinline__ float dot4(float4 a, float4 b) {
    return a.x * b.x + a.y * b.y + a.z * b.z + a.w * b.w;
}

// ksetup:
//  blocks [0,DH): G matrices in TRANSPOSED layout GiT[k*DH+j] = sum_q Wq[(DU+j),q]*Wki[k,q]
//  blocks DH, DH+1: transpose Wvi/Wvs -> WviT/WvsT [q][k]
//  blocks [DH+2, DH+2+B): per-b u-part of qv (bq folded):
//    qu_i[b,k] = sum_q Wki[k,q] * (u[b]@Wq_u + bq)[q];  qu_s likewise.
__global__ __launch_bounds__(256) void ksetup(
    const float* __restrict__ u,
    const float* __restrict__ Wq, const float* __restrict__ bq,
    const float* __restrict__ Wki, const float* __restrict__ Wks,
    const float* __restrict__ Wvi, const float* __restrict__ Wvs,
    float* __restrict__ GiT, float* __restrict__ GsT,
    float* __restrict__ WviT, float* __restrict__ WvsT,
    float* __restrict__ qu_i, float* __restrict__ qu_s)
{
    const int t = threadIdx.x;
    if (blockIdx.x < DH) {
        __shared__ __align__(16) float sWqc[QK];
        const int j = blockIdx.x;
        if (t < QK) sWqc[t] = Wq[(DU + j) * QK + t];
        __syncthreads();
        const int k = t & 127;
        const float* Wk = (t < 128) ? Wki : Wks;
        const float4* Wr = (const float4*)(Wk + k * QK);
        const float4* cq = (const float4*)sWqc;
        float acc = 0.f;
        #pragma unroll
        for (int q4 = 0; q4 < 16; ++q4) acc += dot4(Wr[q4], cq[q4]);
        if (t < 128) GiT[k * DH + j] = acc;
        else GsT[k * DH + j] = acc;
    } else if (blockIdx.x < DH + 2) {
        const float* W = (blockIdx.x == DH) ? Wvi : Wvs;
        float* WT = (blockIdx.x == DH) ? WviT : WvsT;
        for (int i = t; i < DH * QK; i += 256) {
            int kk = i >> 6, q = i & 63;
            WT[q * DH + kk] = W[i];
        }
    } else {
        __shared__ float sPart[4 * QK];
        __shared__ __align__(16) float sQu[QK];
        const int b = blockIdx.x - DH - 2;
        const int lane = t & 63, wave = t >> 6;
        float acc = 0.f;
        const int k0 = wave * 32;
        #pragma unroll 8
        for (int i = 0; i < 32; ++i) {
            int k = k0 + i;
            acc += u[(size_t)b * DU + k] * Wq[k * QK + lane];
        }
        sPart[wave * QK + lane] = acc;
        __syncthreads();
        if (t < QK) sQu[t] = bq[t] + sPart[t] + sPart[64 + t] + sPart[128 + t] + sPart[192 + t];
        __syncthreads();
        const int k = t & 127;
        const float* Wk = (t < 128) ? Wki : Wks;
        const float4* Wr = (const float4*)(Wk + k * QK);
        const float4* cq = (const float4*)sQu;
        float acc2 = 0.f;
        #pragma unroll
        for (int q4 = 0; q4 < 16; ++q4) acc2 += dot4(Wr[q4], cq[q4]);
        if (t < 128) qu_i[(size_t)b * DH + k] = acc2;
        else qu_s[(size_t)b * DH + k] = acc2;
    }
}

// kin: one block per (2 b's, d). H register-resident.
// Thread layout: bb = t>>7 (which b), gg = (t&127)>>5 (row group), col4 = t&31.
// Thread owns rows r = gg + 4k (k < nr), cols 4*col4..4*col4+3 of H[b0+bb].
__global__ __launch_bounds__(256, 5) void kin(
    const float* __restrict__ Hi,   // [D,B,L,DH]
    const float* __restrict__ GiT, const float* __restrict__ GsT,
    const float* __restrict__ qu_i, const float* __restrict__ qu_s,
    const float* __restrict__ WviT, const float* __restrict__ bvi,
    float* __restrict__ qvs_w,      // [D,B,DH]
    float* __restrict__ hi_w)       // [D,B,QK]
{
    __shared__ float4 sP4[256];                  // partials: c, then vagg
    __shared__ __align__(16) float sC0[DH];      // c for b0
    __shared__ __align__(16) float sC1[DH];      // c for b0+1
    __shared__ __align__(16) float sQVi[2 * DH]; // qv_i [bb][k]
    __shared__ float sSc[128];
    __shared__ float sA[128];
    __shared__ __align__(16) float sVagg[2 * DH];
    __shared__ float sPA[256], sPB[256];

    const int b0 = blockIdx.x * 2;
    const int d = blockIdx.y;
    const int t = threadIdx.x;
    const int lane = t & 63, wave = t >> 6;
    const int bb = t >> 7;
    const int tb = t & 127;
    const int gg = tb >> 5;
    const int col4 = t & 31;
    const int nr = (gg < 2) ? 13 : 12;
    const float* sPf = (const float*)sP4;

    // H tile -> registers (coalesced b128)
    const float* Hbase = Hi + ((size_t)d * B + (b0 + bb)) * (L * DH);
    float4 h4[13];
    #pragma unroll
    for (int k = 0; k < 13; ++k)
        if (k < nr) h4[k] = *(const float4*)(Hbase + (gg + 4 * k) * DH + 4 * col4);

    // c partials
    {
        float4 cs = make_float4(0.f, 0.f, 0.f, 0.f);
        #pragma unroll
        for (int k = 0; k < 13; ++k)
            if (k < nr) { cs.x += h4[k].x; cs.y += h4[k].y; cs.z += h4[k].z; cs.w += h4[k].w; }
        sP4[t] = cs;
    }
    __syncthreads();
    {
        const int bbc = t >> 7, col = t & 127;
        float s = sPf[bbc * 512 + col] + sPf[bbc * 512 + 128 + col]
                + sPf[bbc * 512 + 256 + col] + sPf[bbc * 512 + 384 + col];
        float* sc = bbc ? sC1 : sC0;
        sc[col] = s * (1.0f / (float)L);
    }
    __syncthreads();

    // qv = qu + G^T c for both b's; dwordx4 GT-row reads, float4 LDS c reads
    {
        const int mat = t >> 7, k = t & 127;
        const float* GT = mat ? GsT : GiT;
        const float* qum = mat ? qu_s : qu_i;
        float a0 = qum[(size_t)b0 * DH + k];
        float a1 = qum[(size_t)(b0 + 1) * DH + k];
        const float4* Gr = (const float4*)(GT + (size_t)k * DH);
        const float4* c0 = (const float4*)sC0;
        const float4* c1 = (const float4*)sC1;
        #pragma unroll 8
        for (int j4 = 0; j4 < 32; ++j4) {
            float4 g = Gr[j4];
            a0 += dot4(g, c0[j4]);
            a1 += dot4(g, c1[j4]);
        }
        if (mat == 0) { sQVi[k] = a0; sQVi[DH + k] = a1; }
        else {
            qvs_w[((size_t)d * B + b0) * DH + k] = a0;
            qvs_w[((size_t)d * B + b0 + 1) * DH + k] = a1;
        }
    }
    __syncthreads();

    // scores
    {
        float4 qv = ((const float4*)sQVi)[bb * 32 + col4];
        #pragma unroll
        for (int k = 0; k < 13; ++k)
            if (k < nr) {
                float p = dot4(h4[k], qv);
                p = gsum32(p);
                if (col4 == 0) sSc[bb * 64 + gg + 4 * k] = p * 0.125f;
            }
    }
    __syncthreads();
    if (wave < 2) {
        float s = (lane < L) ? sSc[wave * 64 + lane] : -3.0e38f;
        float m = wmax(s);
        float e = (lane < L) ? expf(s - m) : 0.f;
        float ssum = wsum(e);
        if (lane < L) sA[wave * 64 + lane] = e / ssum;
    }
    __syncthreads();

    // vagg partials
    {
        float4 va = make_float4(0.f, 0.f, 0.f, 0.f);
        #pragma unroll
        for (int k = 0; k < 13; ++k)
            if (k < nr) {
                float a = sA[bb * 64 + gg + 4 * k];
                va.x += a * h4[k].x; va.y += a * h4[k].y;
                va.z += a * h4[k].z; va.w += a * h4[k].w;
            }
        sP4[t] = va;
    }
    __syncthreads();
    {
        const int bbc = t >> 7, col = t & 127;
        sVagg[bbc * 128 + col] = sPf[bbc * 512 + col] + sPf[bbc * 512 + 128 + col]
                               + sPf[bbc * 512 + 256 + col] + sPf[bbc * 512 + 384 + col];
    }
    __syncthreads();

    // h_i = vagg @ Wvi + bvi for both b's (WviT dwordx4 reads)
    {
        const int q = t & 63, kq = t >> 6;
        const float4* Wr = (const float4*)(WviT + q * DH + kq * 32);
        const float4* v0 = (const float4*)(sVagg + kq * 32);
        const float4* v1 = (const float4*)(sVagg + DH + kq * 32);
        float a0 = 0.f, a1 = 0.f;
        #pragma unroll
        for (int i = 0; i < 8; ++i) {
            float4 w = Wr[i];
            a0 += dot4(w, v0[i]);
            a1 += dot4(w, v1[i]);
        }
        sPA[kq * 64 + q] = a0;
        sPB[kq * 64 + q] = a1;
    }
    __syncthreads();
    if (t < 128) {
        const int bw = t >> 6, q = t & 63;
        const float* P = bw ? sPB : sPA;
        hi_w[((size_t)d * B + b0 + bw) * QK + q] =
            bvi[q] + P[q] + P[64 + q] + P[128 + q] + P[192 + q];
    }
}

// kstat: segment sums of h per (domain, dim). 64 blocks x 32 rows.
__global__ __launch_bounds__(256) void kstat(
    const float* __restrict__ h, const int* __restrict__ dom_ids,
    float* __restrict__ gsum, float* __restrict__ gsq, float* __restrict__ gcnt)
{
    __shared__ float sS[D * DH], sQ2[D * DH], sCnt[D];
    const int t = threadIdx.x;
    const int b0 = blockIdx.x * 32;
    for (int i = t; i < D * DH; i += 256) { sS[i] = 0.f; sQ2[i] = 0.f; }
    if (t < D) sCnt[t] = 0.f;
    __syncthreads();
    const int col = t & 127, half = t >> 7;
    for (int rr = 0; rr < 16; ++rr) {
        int b = b0 + rr * 2 + half;
        float v = h[(size_t)b * DH + col];
        int dm = dom_ids[b];
        atomicAdd(&sS[dm * DH + col], v);
        atomicAdd(&sQ2[dm * DH + col], v * v);
        if (col == 0) atomicAdd(&sCnt[dm], 1.f);
    }
    __syncthreads();
    for (int i = t; i < D * DH; i += 256) {
        atomicAdd(&gsum[i], sS[i]);
        atomicAdd(&gsq[i], sQ2[i]);
    }
    if (t < D) atomicAdd(&gcnt[t], sCnt[t]);
}

// ksh: one block per b. Shared attention for all 5 domains, Hs register-resident.
__global__ __launch_bounds__(256, 5) void ksh(
    const float* __restrict__ Hs,     // [B,LS,DH]
    const float* __restrict__ qvs_w,  // [D,B,DH]
    const float* __restrict__ WvsT, const float* __restrict__ bvs,
    float* __restrict__ hs_w)         // [D,B,QK]
{
    __shared__ float4 sQV4[160];
    __shared__ float sS[D * 64];
    __shared__ float4 sVP4[640];     // 10 KB: vagg partials / h_s partials
    __shared__ __align__(16) float sVA[D * DH];

    const int b = blockIdx.x;
    const int t = threadIdx.x;
    const int lane = t & 63;
    const int wave = t >> 6;
    const int g = t >> 5;
    const int col4 = t & 31;
    const int nrow = (g < 2) ? 7 : 6;
    float* sBigF = (float*)sVP4;

    const float* Hbase = Hs + (size_t)b * LS * DH;
    float4 h4[7];
    #pragma unroll
    for (int k = 0; k < 7; ++k)
        if (k < nrow) h4[k] = *(const float4*)(Hbase + (g + 8 * k) * DH + 4 * col4);
    if (t < 160) {
        int dd = t >> 5, c4 = t & 31;
        sQV4[t] = *(const float4*)(qvs_w + ((size_t)dd * B + b) * DH + 4 * c4);
    }
    __syncthreads();

    #pragma unroll
    for (int dd = 0; dd < D; ++dd) {
        float4 qv = sQV4[dd * 32 + col4];
        #pragma unroll
        for (int k = 0; k < 7; ++k)
            if (k < nrow) {
                float p = dot4(h4[k], qv);
                p = gsum32(p);
                if (col4 == 0) sS[dd * 64 + g + 8 * k] = p * 0.125f;
            }
    }
    __syncthreads();
    for (int dd = wave; dd < D; dd += 4) {
        float s = (lane < LS) ? sS[dd * 64 + lane] : -3.0e38f;
        float m = wmax(s);
        float e = (lane < LS) ? expf(s - m) : 0.f;
        float ssum = wsum(e);
        if (lane < LS) sS[dd * 64 + lane] = e / ssum;
    }
    __syncthreads();

    // vagg partials: fold g-pairs with shfl_xor(32), halves LDS traffic
    {
        float4 va[D];
        #pragma unroll
        for (int dd = 0; dd < D; ++dd) va[dd] = make_float4(0.f, 0.f, 0.f, 0.f);
        #pragma unroll
        for (int k = 0; k < 7; ++k)
            if (k < nrow) {
                float4 hv = h4[k];
                #pragma unroll
                for (int dd = 0; dd < D; ++dd) {
                    float a = sS[dd * 64 + g + 8 * k];
                    va[dd].x += a * hv.x; va[dd].y += a * hv.y;
                    va[dd].z += a * hv.z; va[dd].w += a * hv.w;
                }
            }
        #pragma unroll
        for (int dd = 0; dd < D; ++dd) {
            va[dd].x += __shfl_xor(va[dd].x, 32, 64);
            va[dd].y += __shfl_xor(va[dd].y, 32, 64);
            va[dd].z += __shfl_xor(va[dd].z, 32, 64);
            va[dd].w += __shfl_xor(va[dd].w, 32, 64);
        }
        if (lane < 32) {
            #pragma unroll
            for (int dd = 0; dd < D; ++dd)
                sVP4[(dd * 4 + wave) * 32 + col4] = va[dd];
        }
    }
    __syncthreads();
    for (int o = t; o < D * DH; o += 256) {
        int dd = o >> 7, col = o & 127;
        float s = 0.f;
        #pragma unroll
        for (int gh = 0; gh < 4; ++gh) s += sBigF[(dd * 4 + gh) * 128 + col];
        sVA[o] = s;
    }
    __syncthreads();

    // h_s = vagg @ Wvs + bvs: 320 outputs x split-k 4, WvsT dwordx4 reads
    #pragma unroll
    for (int j = 0; j < 5; ++j) {
        int tau = t + j * 256;
        int kq = tau / 320;
        int o = tau - kq * 320;
        int dd = o >> 6, q = o & 63;
        const float4* Wr = (const float4*)(WvsT + q * DH + kq * 32);
        const float4* vv = (const float4*)(sVA + dd * DH + kq * 32);
        float acc = 0.f;
        #pragma unroll
        for (int i = 0; i < 8; ++i) acc += dot4(Wr[i], vv[i]);
        sBigF[tau] = acc;
    }
    __syncthreads();
    for (int o = t; o < D * QK; o += 256) {
        int dd = o >> 6, q = o & 63;
        hs_w[((size_t)dd * B + b) * QK + q] =
            bvs[q] + sBigF[o] + sBigF[o + 320] + sBigF[o + 640] + sBigF[o + 960];
    }
}

// kfin: one block per b. Loss, z, gb, AdaNorm epilogue.
__global__ __launch_bounds__(256) void kfin(
    const float* __restrict__ h, const int* __restrict__ dom_ids,
    const float* __restrict__ hi_w, const float* __restrict__ hs_w,
    const float* __restrict__ Wf, const float* __restrict__ bf,
    const float* __restrict__ Wgb, const float* __restrict__ bgb,
    const float* __restrict__ gsum, const float* __restrict__ gsq,
    const float* __restrict__ gcnt,
    float* __restrict__ out, float* __restrict__ loss_out)
{
    __shared__ __align__(16) float sHI[D * QK];
    __shared__ __align__(16) float sHS[D * QK];
    __shared__ float sInv[16], sSim[32], sZ[QK], sPartZ[256], sGB[256];

    const int b = blockIdx.x;
    const int t = threadIdx.x;
    const int lane = t & 63;
    const int wave = t >> 6;
    const int dm = dom_ids[b];

    if (t < 80) {
        int dd = t >> 4, q4 = t & 15;
        ((float4*)sHI)[t] = *(const float4*)(hi_w + ((size_t)dd * B + b) * QK + 4 * q4);
        ((float4*)sHS)[t] = *(const float4*)(hs_w + ((size_t)dd * B + b) * QK + 4 * q4);
    }
    __syncthreads();

    for (int v = wave; v < 2 * D; v += 4) {
        float x = (v < D) ? sHI[v * QK + lane] : sHS[(v - D) * QK + lane];
        float ss = wsum(x * x);
        if (lane == 0) sInv[v] = 1.0f / fmaxf(sqrtf(ss), 1e-12f);
    }
    __syncthreads();
    for (int p = wave; p < 30; p += 4) {
        float s;
        if (p < 25) {
            int dd = p / 5, e = p - dd * 5;
            s = wsum(sHI[dd * QK + lane] * sHI[e * QK + lane] * sInv[dd] * sInv[e]);
        } else {
            int dd = p - 25;
            s = wsum(sHI[dd * QK + lane] * sHS[dd * QK + lane] * sInv[dd] * sInv[D + dd]);
        }
        if (lane == 0) sSim[p] = s;
    }
    __syncthreads();
    if (t == 0) {
        float tot = 0.f;
        #pragma unroll
        for (int dd = 0; dd < D; ++dd) {
            float den = 0.f;
            #pragma unroll
            for (int e = 0; e < D; ++e) den += expf(sSim[dd * 5 + e]);
            tot += logf(expf(sSim[25 + dd]) / (den + 1e-8f) + 1e-8f);
        }
        atomicAdd(loss_out, -tot / (float)(B * D));
    }

    // z = [h_i[dm], h_s[dm]] @ Wf + bf
    {
        const int kq = wave, q = lane;
        float acc = 0.f;
        const int k0 = kq * 32;
        #pragma unroll 8
        for (int i = 0; i < 32; ++i) {
            int k = k0 + i;
            float x = (k < QK) ? sHI[dm * QK + k] : sHS[dm * QK + (k - QK)];
            acc += x * Wf[k * CD + q];
        }
        sPartZ[t] = acc;
    }
    __syncthreads();
    if (t < QK) sZ[t] = bf[t] + sPartZ[t] + sPartZ[64 + t] + sPartZ[128 + t] + sPartZ[192 + t];
    __syncthreads();

    {
        float acc = bgb[t];
        #pragma unroll 8
        for (int k = 0; k < CD; ++k) acc += sZ[k] * Wgb[k * (2 * DH) + t];
        sGB[t] = acc;
    }
    __syncthreads();

    if (t < DH) {
        float c = fmaxf(gcnt[dm], 1.0f);
        float mu = gsum[dm * DH + t] / c;
        float va = gsq[dm * DH + t] / c - mu * mu;
        float hv = h[(size_t)b * DH + t];
        float hn = (hv - mu) / sqrtf(va + EPS);
        out[(size_t)b * DH + t] = sGB[t] * hn + sGB[DH + t] + hv;
    }
}

extern "C" void kernel_launch(void* const* d_in, const int* in_sizes, int n_in,
                              void* d_out, int out_size, void* d_ws, size_t ws_size,
                              hipStream_t stream)
{
    (void)in_sizes; (void)n_in; (void)out_size; (void)ws_size;
    const float* u   = (const float*)d_in[0];
    const float* Hi  = (const float*)d_in[1];
    const float* Hs  = (const float*)d_in[2];
    const float* h   = (const float*)d_in[3];
    const int*   dom = (const int*)d_in[4];
    const float* Wq  = (const float*)d_in[5];
    const float* bq  = (const float*)d_in[6];
    const float* Wki = (const float*)d_in[7];
    // d_in[8] = bki: unused (softmax shift-invariance)
    const float* Wvi = (const float*)d_in[9];
    const float* bvi = (const float*)d_in[10];
    const float* Wks = (const float*)d_in[11];
    // d_in[12] = bks: unused (softmax shift-invariance)
    const float* Wvs = (const float*)d_in[13];
    const float* bvs = (const float*)d_in[14];
    const float* Wf  = (const float*)d_in[15];
    const float* bf  = (const float*)d_in[16];
    const float* Wgb = (const float*)d_in[17];
    const float* bgb = (const float*)d_in[18];

    float* out = (float*)d_out;
    float* loss_out = out + (size_t)B * DH;

    float* ws = (float*)d_ws;
    float* GiT   = ws;                                // DH*DH
    float* GsT   = GiT + DH * DH;                     // DH*DH
    float* WviT  = GsT + DH * DH;                     // QK*DH
    float* WvsT  = WviT + QK * DH;                    // QK*DH
    float* qu_i  = WvsT + QK * DH;                    // B*DH
    float* qu_s  = qu_i + (size_t)B * DH;             // B*DH
    float* qvs_w = qu_s + (size_t)B * DH;             // D*B*DH
    float* hi_w  = qvs_w + (size_t)D * B * DH;        // D*B*QK
    float* hs_w  = hi_w + (size_t)D * B * QK;         // D*B*QK
    float* gsum  = hs_w + (size_t)D * B * QK;         // D*DH
    float* gsq   = gsum + D * DH;                     // D*DH
    float* gcnt  = gsq + D * DH;                      // 8

    hipMemsetAsync(gsum, 0, (size_t)(2 * D * DH + 8) * sizeof(float), stream);
    hipMemsetAsync(loss_out, 0, sizeof(float), stream);

    hipLaunchKernelGGL(ksetup, dim3(DH + 2 + B), dim3(256), 0, stream,
                       u, Wq, bq, Wki, Wks, Wvi, Wvs, GiT, GsT, WviT, WvsT, qu_i, qu_s);
    hipLaunchKernelGGL(kstat, dim3(B / 32), dim3(256), 0, stream, h, dom, gsum, gsq, gcnt);
    hipLaunchKernelGGL(kin, dim3(B / 2, D), dim3(256), 0, stream,
                       Hi, GiT, GsT, qu_i, qu_s, WviT, bvi, qvs_w, hi_w);
    hipLaunchKernelGGL(ksh, dim3(B), dim3(256), 0, stream, Hs, qvs_w, WvsT, bvs, hs_w);
    hipLaunchKernelGGL(kfin, dim3(B), dim3(256), 0, stream,
                       h, dom, hi_w, hs_w, Wf, bf, Wgb, bgb, gsum, gsq, gcnt, out, loss_out);
}

// Round 2
// 623.007 us; speedup vs baseline: 1.0065x; 1.0065x over previous
//
#include <hip/hip_runtime.h>
#include <math.h>

#define D 5
#define B 2048
#define L 50
#define LS 50
#define DH 128
#define DU 128
#define QK 64
#define CD 64
#define EPS 1e-5f

__device__ __forceinline__ float wsum(float v) {
    v += __shfl_xor(v, 1, 64);
    v += __shfl_xor(v, 2, 64);
    v += __shfl_xor(v, 4, 64);
    v += __shfl_xor(v, 8, 64);
    v += __shfl_xor(v, 16, 64);
    v += __shfl_xor(v, 32, 64);
    return v;
}

__device__ __forceinline__ float wmax(float v) {
    v = fmaxf(v, __shfl_xor(v, 1, 64));
    v = fmaxf(v, __shfl_xor(v, 2, 64));
    v = fmaxf(v, __shfl_xor(v, 4, 64));
    v = fmaxf(v, __shfl_xor(v, 8, 64));
    v = fmaxf(v, __shfl_xor(v, 16, 64));
    v = fmaxf(v, __shfl_xor(v, 32, 64));
    return v;
}

// reduction across a 32-lane group (xor bits 0..4 keep bit5 invariant)
__device__ __forceinline__ float gsum32(float v) {
    v += __shfl_xor(v, 1, 64);
    v += __shfl_xor(v, 2, 64);
    v += __shfl_xor(v, 4, 64);
    v += __shfl_xor(v, 8, 64);
    v += __shfl_xor(v, 16, 64);
    return v;
}

__device__ __forceinline__ float dot4(float4 a, float4 b) {
    return a.x * b.x + a.y * b.y + a.z * b.z + a.w * b.w;
}

// ksetup:
//  blocks [0,DH): G matrices in TRANSPOSED layout GiT[k*DH+j] = sum_q Wq[(DU+j),q]*Wki[k,q]
//  blocks DH, DH+1: transpose Wvi/Wvs -> WviT/WvsT [q][k]
//  blocks [DH+2, DH+2+B): per-b u-part of qv (bq folded):
//    qu_i[b,k] = sum_q Wki[k,q] * (u[b]@Wq_u + bq)[q];  qu_s likewise.
__global__ __launch_bounds__(256) void ksetup(
    const float* __restrict__ u,
    const float* __restrict__ Wq, const float* __restrict__ bq,
    const float* __restrict__ Wki, const float* __restrict__ Wks,
    const float* __restrict__ Wvi, const float* __restrict__ Wvs,
    float* __restrict__ GiT, float* __restrict__ GsT,
    float* __restrict__ WviT, float* __restrict__ WvsT,
    float* __restrict__ qu_i, float* __restrict__ qu_s)
{
    const int t = threadIdx.x;
    if (blockIdx.x < DH) {
        __shared__ __align__(16) float sWqc[QK];
        const int j = blockIdx.x;
        if (t < QK) sWqc[t] = Wq[(DU + j) * QK + t];
        __syncthreads();
        const int k = t & 127;
        const float* Wk = (t < 128) ? Wki : Wks;
        const float4* Wr = (const float4*)(Wk + k * QK);
        const float4* cq = (const float4*)sWqc;
        float acc = 0.f;
        #pragma unroll
        for (int q4 = 0; q4 < 16; ++q4) acc += dot4(Wr[q4], cq[q4]);
        if (t < 128) GiT[k * DH + j] = acc;
        else GsT[k * DH + j] = acc;
    } else if (blockIdx.x < DH + 2) {
        const float* W = (blockIdx.x == DH) ? Wvi : Wvs;
        float* WT = (blockIdx.x == DH) ? WviT : WvsT;
        for (int i = t; i < DH * QK; i += 256) {
            int kk = i >> 6, q = i & 63;
            WT[q * DH + kk] = W[i];
        }
    } else {
        __shared__ float sPart[4 * QK];
        __shared__ __align__(16) float sQu[QK];
        const int b = blockIdx.x - DH - 2;
        const int lane = t & 63, wave = t >> 6;
        float acc = 0.f;
        const int k0 = wave * 32;
        #pragma unroll 8
        for (int i = 0; i < 32; ++i) {
            int k = k0 + i;
            acc += u[(size_t)b * DU + k] * Wq[k * QK + lane];
        }
        sPart[wave * QK + lane] = acc;
        __syncthreads();
        if (t < QK) sQu[t] = bq[t] + sPart[t] + sPart[64 + t] + sPart[128 + t] + sPart[192 + t];
        __syncthreads();
        const int k = t & 127;
        const float* Wk = (t < 128) ? Wki : Wks;
        const float4* Wr = (const float4*)(Wk + k * QK);
        const float4* cq = (const float4*)sQu;
        float acc2 = 0.f;
        #pragma unroll
        for (int q4 = 0; q4 < 16; ++q4) acc2 += dot4(Wr[q4], cq[q4]);
        if (t < 128) qu_i[(size_t)b * DH + k] = acc2;
        else qu_s[(size_t)b * DH + k] = acc2;
    }
}

// kin: one block per (2 b's, d). H register-resident.
// Thread layout: bb = t>>7 (which b), gg = (t&127)>>5 (row group), col4 = t&31.
// Thread owns rows r = gg + 4k (k < nr), cols 4*col4..4*col4+3 of H[b0+bb].
// NOTE: __launch_bounds__(256,4) — at 5 the allocator spills h4[13] to scratch
// (measured: VGPR_Count 48, kin 150->176us). 4 gives 128-VGPR budget, no spill.
__global__ __launch_bounds__(256, 4) void kin(
    const float* __restrict__ Hi,   // [D,B,L,DH]
    const float* __restrict__ GiT, const float* __restrict__ GsT,
    const float* __restrict__ qu_i, const float* __restrict__ qu_s,
    const float* __restrict__ WviT, const float* __restrict__ bvi,
    float* __restrict__ qvs_w,      // [D,B,DH]
    float* __restrict__ hi_w)       // [D,B,QK]
{
    __shared__ float4 sP4[256];                  // partials: c, then vagg
    __shared__ __align__(16) float sC0[DH];      // c for b0
    __shared__ __align__(16) float sC1[DH];      // c for b0+1
    __shared__ __align__(16) float sQVi[2 * DH]; // qv_i [bb][k]
    __shared__ float sSc[128];
    __shared__ float sA[128];
    __shared__ __align__(16) float sVagg[2 * DH];
    __shared__ float sPA[256], sPB[256];

    const int b0 = blockIdx.x * 2;
    const int d = blockIdx.y;
    const int t = threadIdx.x;
    const int lane = t & 63, wave = t >> 6;
    const int bb = t >> 7;
    const int tb = t & 127;
    const int gg = tb >> 5;
    const int col4 = t & 31;
    const int nr = (gg < 2) ? 13 : 12;
    const float* sPf = (const float*)sP4;

    // H tile -> registers (coalesced b128)
    const float* Hbase = Hi + ((size_t)d * B + (b0 + bb)) * (L * DH);
    float4 h4[13];
    #pragma unroll
    for (int k = 0; k < 13; ++k)
        if (k < nr) h4[k] = *(const float4*)(Hbase + (gg + 4 * k) * DH + 4 * col4);

    // c partials
    {
        float4 cs = make_float4(0.f, 0.f, 0.f, 0.f);
        #pragma unroll
        for (int k = 0; k < 13; ++k)
            if (k < nr) { cs.x += h4[k].x; cs.y += h4[k].y; cs.z += h4[k].z; cs.w += h4[k].w; }
        sP4[t] = cs;
    }
    __syncthreads();
    {
        const int bbc = t >> 7, col = t & 127;
        float s = sPf[bbc * 512 + col] + sPf[bbc * 512 + 128 + col]
                + sPf[bbc * 512 + 256 + col] + sPf[bbc * 512 + 384 + col];
        float* sc = bbc ? sC1 : sC0;
        sc[col] = s * (1.0f / (float)L);
    }
    __syncthreads();

    // qv = qu + G^T c for both b's; dwordx4 GT-row reads, float4 LDS c reads
    {
        const int mat = t >> 7, k = t & 127;
        const float* GT = mat ? GsT : GiT;
        const float* qum = mat ? qu_s : qu_i;
        float a0 = qum[(size_t)b0 * DH + k];
        float a1 = qum[(size_t)(b0 + 1) * DH + k];
        const float4* Gr = (const float4*)(GT + (size_t)k * DH);
        const float4* c0 = (const float4*)sC0;
        const float4* c1 = (const float4*)sC1;
        #pragma unroll 8
        for (int j4 = 0; j4 < 32; ++j4) {
            float4 g = Gr[j4];
            a0 += dot4(g, c0[j4]);
            a1 += dot4(g, c1[j4]);
        }
        if (mat == 0) { sQVi[k] = a0; sQVi[DH + k] = a1; }
        else {
            qvs_w[((size_t)d * B + b0) * DH + k] = a0;
            qvs_w[((size_t)d * B + b0 + 1) * DH + k] = a1;
        }
    }
    __syncthreads();

    // scores
    {
        float4 qv = ((const float4*)sQVi)[bb * 32 + col4];
        #pragma unroll
        for (int k = 0; k < 13; ++k)
            if (k < nr) {
                float p = dot4(h4[k], qv);
                p = gsum32(p);
                if (col4 == 0) sSc[bb * 64 + gg + 4 * k] = p * 0.125f;
            }
    }
    __syncthreads();
    if (wave < 2) {
        float s = (lane < L) ? sSc[wave * 64 + lane] : -3.0e38f;
        float m = wmax(s);
        float e = (lane < L) ? expf(s - m) : 0.f;
        float ssum = wsum(e);
        if (lane < L) sA[wave * 64 + lane] = e / ssum;
    }
    __syncthreads();

    // vagg partials
    {
        float4 va = make_float4(0.f, 0.f, 0.f, 0.f);
        #pragma unroll
        for (int k = 0; k < 13; ++k)
            if (k < nr) {
                float a = sA[bb * 64 + gg + 4 * k];
                va.x += a * h4[k].x; va.y += a * h4[k].y;
                va.z += a * h4[k].z; va.w += a * h4[k].w;
            }
        sP4[t] = va;
    }
    __syncthreads();
    {
        const int bbc = t >> 7, col = t & 127;
        sVagg[bbc * 128 + col] = sPf[bbc * 512 + col] + sPf[bbc * 512 + 128 + col]
                               + sPf[bbc * 512 + 256 + col] + sPf[bbc * 512 + 384 + col];
    }
    __syncthreads();

    // h_i = vagg @ Wvi + bvi for both b's (WviT dwordx4 reads)
    {
        const int q = t & 63, kq = t >> 6;
        const float4* Wr = (const float4*)(WviT + q * DH + kq * 32);
        const float4* v0 = (const float4*)(sVagg + kq * 32);
        const float4* v1 = (const float4*)(sVagg + DH + kq * 32);
        float a0 = 0.f, a1 = 0.f;
        #pragma unroll
        for (int i = 0; i < 8; ++i) {
            float4 w = Wr[i];
            a0 += dot4(w, v0[i]);
            a1 += dot4(w, v1[i]);
        }
        sPA[kq * 64 + q] = a0;
        sPB[kq * 64 + q] = a1;
    }
    __syncthreads();
    if (t < 128) {
        const int bw = t >> 6, q = t & 63;
        const float* P = bw ? sPB : sPA;
        hi_w[((size_t)d * B + b0 + bw) * QK + q] =
            bvi[q] + P[q] + P[64 + q] + P[128 + q] + P[192 + q];
    }
}

// kstat: segment sums of h per (domain, dim). 64 blocks x 32 rows.
__global__ __launch_bounds__(256) void kstat(
    const float* __restrict__ h, const int* __restrict__ dom_ids,
    float* __restrict__ gsum, float* __restrict__ gsq, float* __restrict__ gcnt)
{
    __shared__ float sS[D * DH], sQ2[D * DH], sCnt[D];
    const int t = threadIdx.x;
    const int b0 = blockIdx.x * 32;
    for (int i = t; i < D * DH; i += 256) { sS[i] = 0.f; sQ2[i] = 0.f; }
    if (t < D) sCnt[t] = 0.f;
    __syncthreads();
    const int col = t & 127, half = t >> 7;
    for (int rr = 0; rr < 16; ++rr) {
        int b = b0 + rr * 2 + half;
        float v = h[(size_t)b * DH + col];
        int dm = dom_ids[b];
        atomicAdd(&sS[dm * DH + col], v);
        atomicAdd(&sQ2[dm * DH + col], v * v);
        if (col == 0) atomicAdd(&sCnt[dm], 1.f);
    }
    __syncthreads();
    for (int i = t; i < D * DH; i += 256) {
        atomicAdd(&gsum[i], sS[i]);
        atomicAdd(&gsq[i], sQ2[i]);
    }
    if (t < D) atomicAdd(&gcnt[t], sCnt[t]);
}

// ksh: one block per b. Shared attention for all 5 domains, Hs register-resident.
// __launch_bounds__(256,4): at 5 the reduced VGPR budget risks spilling
// h4[7]+va[5] float4 live state (see kin note).
__global__ __launch_bounds__(256, 4) void ksh(
    const float* __restrict__ Hs,     // [B,LS,DH]
    const float* __restrict__ qvs_w,  // [D,B,DH]
    const float* __restrict__ WvsT, const float* __restrict__ bvs,
    float* __restrict__ hs_w)         // [D,B,QK]
{
    __shared__ float4 sQV4[160];
    __shared__ float sS[D * 64];
    __shared__ float4 sVP4[640];     // 10 KB: vagg partials / h_s partials
    __shared__ __align__(16) float sVA[D * DH];

    const int b = blockIdx.x;
    const int t = threadIdx.x;
    const int lane = t & 63;
    const int wave = t >> 6;
    const int g = t >> 5;
    const int col4 = t & 31;
    const int nrow = (g < 2) ? 7 : 6;
    float* sBigF = (float*)sVP4;

    const float* Hbase = Hs + (size_t)b * LS * DH;
    float4 h4[7];
    #pragma unroll
    for (int k = 0; k < 7; ++k)
        if (k < nrow) h4[k] = *(const float4*)(Hbase + (g + 8 * k) * DH + 4 * col4);
    if (t < 160) {
        int dd = t >> 5, c4 = t & 31;
        sQV4[t] = *(const float4*)(qvs_w + ((size_t)dd * B + b) * DH + 4 * c4);
    }
    __syncthreads();

    #pragma unroll
    for (int dd = 0; dd < D; ++dd) {
        float4 qv = sQV4[dd * 32 + col4];
        #pragma unroll
        for (int k = 0; k < 7; ++k)
            if (k < nrow) {
                float p = dot4(h4[k], qv);
                p = gsum32(p);
                if (col4 == 0) sS[dd * 64 + g + 8 * k] = p * 0.125f;
            }
    }
    __syncthreads();
    for (int dd = wave; dd < D; dd += 4) {
        float s = (lane < LS) ? sS[dd * 64 + lane] : -3.0e38f;
        float m = wmax(s);
        float e = (lane < LS) ? expf(s - m) : 0.f;
        float ssum = wsum(e);
        if (lane < LS) sS[dd * 64 + lane] = e / ssum;
    }
    __syncthreads();

    // vagg partials: fold g-pairs with shfl_xor(32), halves LDS traffic
    {
        float4 va[D];
        #pragma unroll
        for (int dd = 0; dd < D; ++dd) va[dd] = make_float4(0.f, 0.f, 0.f, 0.f);
        #pragma unroll
        for (int k = 0; k < 7; ++k)
            if (k < nrow) {
                float4 hv = h4[k];
                #pragma unroll
                for (int dd = 0; dd < D; ++dd) {
                    float a = sS[dd * 64 + g + 8 * k];
                    va[dd].x += a * hv.x; va[dd].y += a * hv.y;
                    va[dd].z += a * hv.z; va[dd].w += a * hv.w;
                }
            }
        #pragma unroll
        for (int dd = 0; dd < D; ++dd) {
            va[dd].x += __shfl_xor(va[dd].x, 32, 64);
            va[dd].y += __shfl_xor(va[dd].y, 32, 64);
            va[dd].z += __shfl_xor(va[dd].z, 32, 64);
            va[dd].w += __shfl_xor(va[dd].w, 32, 64);
        }
        if (lane < 32) {
            #pragma unroll
            for (int dd = 0; dd < D; ++dd)
                sVP4[(dd * 4 + wave) * 32 + col4] = va[dd];
        }
    }
    __syncthreads();
    for (int o = t; o < D * DH; o += 256) {
        int dd = o >> 7, col = o & 127;
        float s = 0.f;
        #pragma unroll
        for (int gh = 0; gh < 4; ++gh) s += sBigF[(dd * 4 + gh) * 128 + col];
        sVA[o] = s;
    }
    __syncthreads();

    // h_s = vagg @ Wvs + bvs: 320 outputs x split-k 4, WvsT dwordx4 reads
    #pragma unroll
    for (int j = 0; j < 5; ++j) {
        int tau = t + j * 256;
        int kq = tau / 320;
        int o = tau - kq * 320;
        int dd = o >> 6, q = o & 63;
        const float4* Wr = (const float4*)(WvsT + q * DH + kq * 32);
        const float4* vv = (const float4*)(sVA + dd * DH + kq * 32);
        float acc = 0.f;
        #pragma unroll
        for (int i = 0; i < 8; ++i) acc += dot4(Wr[i], vv[i]);
        sBigF[tau] = acc;
    }
    __syncthreads();
    for (int o = t; o < D * QK; o += 256) {
        int dd = o >> 6, q = o & 63;
        hs_w[((size_t)dd * B + b) * QK + q] =
            bvs[q] + sBigF[o] + sBigF[o + 320] + sBigF[o + 640] + sBigF[o + 960];
    }
}

// kfin: one block per b. Loss, z, gb, AdaNorm epilogue.
__global__ __launch_bounds__(256) void kfin(
    const float* __restrict__ h, const int* __restrict__ dom_ids,
    const float* __restrict__ hi_w, const float* __restrict__ hs_w,
    const float* __restrict__ Wf, const float* __restrict__ bf,
    const float* __restrict__ Wgb, const float* __restrict__ bgb,
    const float* __restrict__ gsum, const float* __restrict__ gsq,
    const float* __restrict__ gcnt,
    float* __restrict__ out, float* __restrict__ loss_out)
{
    __shared__ __align__(16) float sHI[D * QK];
    __shared__ __align__(16) float sHS[D * QK];
    __shared__ float sInv[16], sSim[32], sZ[QK], sPartZ[256], sGB[256];

    const int b = blockIdx.x;
    const int t = threadIdx.x;
    const int lane = t & 63;
    const int wave = t >> 6;
    const int dm = dom_ids[b];

    if (t < 80) {
        int dd = t >> 4, q4 = t & 15;
        ((float4*)sHI)[t] = *(const float4*)(hi_w + ((size_t)dd * B + b) * QK + 4 * q4);
        ((float4*)sHS)[t] = *(const float4*)(hs_w + ((size_t)dd * B + b) * QK + 4 * q4);
    }
    __syncthreads();

    for (int v = wave; v < 2 * D; v += 4) {
        float x = (v < D) ? sHI[v * QK + lane] : sHS[(v - D) * QK + lane];
        float ss = wsum(x * x);
        if (lane == 0) sInv[v] = 1.0f / fmaxf(sqrtf(ss), 1e-12f);
    }
    __syncthreads();
    for (int p = wave; p < 30; p += 4) {
        float s;
        if (p < 25) {
            int dd = p / 5, e = p - dd * 5;
            s = wsum(sHI[dd * QK + lane] * sHI[e * QK + lane] * sInv[dd] * sInv[e]);
        } else {
            int dd = p - 25;
            s = wsum(sHI[dd * QK + lane] * sHS[dd * QK + lane] * sInv[dd] * sInv[D + dd]);
        }
        if (lane == 0) sSim[p] = s;
    }
    __syncthreads();
    if (t == 0) {
        float tot = 0.f;
        #pragma unroll
        for (int dd = 0; dd < D; ++dd) {
            float den = 0.f;
            #pragma unroll
            for (int e = 0; e < D; ++e) den += expf(sSim[dd * 5 + e]);
            tot += logf(expf(sSim[25 + dd]) / (den + 1e-8f) + 1e-8f);
        }
        atomicAdd(loss_out, -tot / (float)(B * D));
    }

    // z = [h_i[dm], h_s[dm]] @ Wf + bf
    {
        const int kq = wave, q = lane;
        float acc = 0.f;
        const int k0 = kq * 32;
        #pragma unroll 8
        for (int i = 0; i < 32; ++i) {
            int k = k0 + i;
            float x = (k < QK) ? sHI[dm * QK + k] : sHS[dm * QK + (k - QK)];
            acc += x * Wf[k * CD + q];
        }
        sPartZ[t] = acc;
    }
    __syncthreads();
    if (t < QK) sZ[t] = bf[t] + sPartZ[t] + sPartZ[64 + t] + sPartZ[128 + t] + sPartZ[192 + t];
    __syncthreads();

    {
        float acc = bgb[t];
        #pragma unroll 8
        for (int k = 0; k < CD; ++k) acc += sZ[k] * Wgb[k * (2 * DH) + t];
        sGB[t] = acc;
    }
    __syncthreads();

    if (t < DH) {
        float c = fmaxf(gcnt[dm], 1.0f);
        float mu = gsum[dm * DH + t] / c;
        float va = gsq[dm * DH + t] / c - mu * mu;
        float hv = h[(size_t)b * DH + t];
        float hn = (hv - mu) / sqrtf(va + EPS);
        out[(size_t)b * DH + t] = sGB[t] * hn + sGB[DH + t] + hv;
    }
}

extern "C" void kernel_launch(void* const* d_in, const int* in_sizes, int n_in,
                              void* d_out, int out_size, void* d_ws, size_t ws_size,
                              hipStream_t stream)
{
    (void)in_sizes; (void)n_in; (void)out_size; (void)ws_size;
    const float* u   = (const float*)d_in[0];
    const float* Hi  = (const float*)d_in[1];
    const float* Hs  = (const float*)d_in[2];
    const float* h   = (const float*)d_in[3];
    const int*   dom = (const int*)d_in[4];
    const float* Wq  = (const float*)d_in[5];
    const float* bq  = (const float*)d_in[6];
    const float* Wki = (const float*)d_in[7];
    // d_in[8] = bki: unused (softmax shift-invariance)
    const float* Wvi = (const float*)d_in[9];
    const float* bvi = (const float*)d_in[10];
    const float* Wks = (const float*)d_in[11];
    // d_in[12] = bks: unused (softmax shift-invariance)
    const float* Wvs = (const float*)d_in[13];
    const float* bvs = (const float*)d_in[14];
    const float* Wf  = (const float*)d_in[15];
    const float* bf  = (const float*)d_in[16];
    const float* Wgb = (const float*)d_in[17];
    const float* bgb = (const float*)d_in[18];

    float* out = (float*)d_out;
    float* loss_out = out + (size_t)B * DH;

    float* ws = (float*)d_ws;
    float* GiT   = ws;                                // DH*DH
    float* GsT   = GiT + DH * DH;                     // DH*DH
    float* WviT  = GsT + DH * DH;                     // QK*DH
    float* WvsT  = WviT + QK * DH;                    // QK*DH
    float* qu_i  = WvsT + QK * DH;                    // B*DH
    float* qu_s  = qu_i + (size_t)B * DH;             // B*DH
    float* qvs_w = qu_s + (size_t)B * DH;             // D*B*DH
    float* hi_w  = qvs_w + (size_t)D * B * DH;        // D*B*QK
    float* hs_w  = hi_w + (size_t)D * B * QK;         // D*B*QK
    float* gsum  = hs_w + (size_t)D * B * QK;         // D*DH
    float* gsq   = gsum + D * DH;                     // D*DH
    float* gcnt  = gsq + D * DH;                      // 8

    hipMemsetAsync(gsum, 0, (size_t)(2 * D * DH + 8) * sizeof(float), stream);
    hipMemsetAsync(loss_out, 0, sizeof(float), stream);

    hipLaunchKernelGGL(ksetup, dim3(DH + 2 + B), dim3(256), 0, stream,
                       u, Wq, bq, Wki, Wks, Wvi, Wvs, GiT, GsT, WviT, WvsT, qu_i, qu_s);
    hipLaunchKernelGGL(kstat, dim3(B / 32), dim3(256), 0, stream, h, dom, gsum, gsq, gcnt);
    hipLaunchKernelGGL(kin, dim3(B / 2, D), dim3(256), 0, stream,
                       Hi, GiT, GsT, qu_i, qu_s, WviT, bvi, qvs_w, hi_w);
    hipLaunchKernelGGL(ksh, dim3(B), dim3(256), 0, stream, Hs, qvs_w, WvsT, bvs, hs_w);
    hipLaunchKernelGGL(kfin, dim3(B), dim3(256), 0, stream,
                       h, dom, hi_w, hs_w, Wf, bf, Wgb, bgb, gsum, gsq, gcnt, out, loss_out);
}

// Round 3
// 556.993 us; speedup vs baseline: 1.1258x; 1.1185x over previous
//
#include <hip/hip_runtime.h>
#include <math.h>

#define D 5
#define B 2048
#define L 50
#define LS 50
#define DH 128
#define DU 128
#define QK 64
#define CD 64
#define EPS 1e-5f

__device__ __forceinline__ float wsum(float v) {
    v += __shfl_xor(v, 1, 64);
    v += __shfl_xor(v, 2, 64);
    v += __shfl_xor(v, 4, 64);
    v += __shfl_xor(v, 8, 64);
    v += __shfl_xor(v, 16, 64);
    v += __shfl_xor(v, 32, 64);
    return v;
}

__device__ __forceinline__ float wmax(float v) {
    v = fmaxf(v, __shfl_xor(v, 1, 64));
    v = fmaxf(v, __shfl_xor(v, 2, 64));
    v = fmaxf(v, __shfl_xor(v, 4, 64));
    v = fmaxf(v, __shfl_xor(v, 8, 64));
    v = fmaxf(v, __shfl_xor(v, 16, 64));
    v = fmaxf(v, __shfl_xor(v, 32, 64));
    return v;
}

// reduction across a 32-lane group (xor bits 0..4 keep bit5 invariant)
__device__ __forceinline__ float gsum32(float v) {
    v += __shfl_xor(v, 1, 64);
    v += __shfl_xor(v, 2, 64);
    v += __shfl_xor(v, 4, 64);
    v += __shfl_xor(v, 8, 64);
    v += __shfl_xor(v, 16, 64);
    return v;
}

__device__ __forceinline__ float dot4(float4 a, float4 b) {
    return a.x * b.x + a.y * b.y + a.z * b.z + a.w * b.w;
}

// ksetup: blocks 0..127 compute G matrices (j-major, coalesced-consumable):
//   Gi[j*DH+k] = sum_q Wq[(DU+j),q] * Wki[k,q];  Gs likewise with Wks.
// blocks 128.. compute per-b u-part of qv (bq folded here):
//   qu_i[b,k] = sum_q Wki[k,q] * (u[b]@Wq_u + bq)[q];  qu_s likewise.
// NOTE: G is deliberately j-major and consumed as G[j*DH+k] with lane=k:
// 64 consecutive floats per wave-instr (4 cache lines). The "obvious"
// per-lane float4 of a k-major GT was measured WORSE (+20us on kin):
// 512B lane stride = 64 lines per wave-instr. Coalescing across lanes
// beats per-lane vectorization when they conflict.
__global__ __launch_bounds__(256) void ksetup(
    const float* __restrict__ u,
    const float* __restrict__ Wq, const float* __restrict__ bq,
    const float* __restrict__ Wki, const float* __restrict__ Wks,
    float* __restrict__ Gi, float* __restrict__ Gs,
    float* __restrict__ qu_i, float* __restrict__ qu_s)
{
    const int t = threadIdx.x;
    if (blockIdx.x < DH) {
        __shared__ float sWqc[QK];
        const int j = blockIdx.x;
        if (t < QK) sWqc[t] = Wq[(DU + j) * QK + t];
        __syncthreads();
        const int k = t & 127;
        const float* Wk = (t < 128) ? Wki : Wks;
        const float4* Wr = (const float4*)(Wk + k * QK);
        const float4* cq = (const float4*)sWqc;
        float acc = 0.f;
        #pragma unroll
        for (int q4 = 0; q4 < 16; ++q4) acc += dot4(Wr[q4], cq[q4]);
        if (t < 128) Gi[j * DH + k] = acc;
        else Gs[j * DH + k] = acc;
    } else {
        __shared__ float sPart[4 * QK];
        __shared__ float sQu[QK];
        const int b = blockIdx.x - DH;
        const int lane = t & 63, wave = t >> 6;
        float acc = 0.f;
        const int k0 = wave * 32;
        #pragma unroll 8
        for (int i = 0; i < 32; ++i) {
            int k = k0 + i;
            acc += u[(size_t)b * DU + k] * Wq[k * QK + lane];
        }
        sPart[wave * QK + lane] = acc;
        __syncthreads();
        if (t < QK) sQu[t] = bq[t] + sPart[t] + sPart[64 + t] + sPart[128 + t] + sPart[192 + t];
        __syncthreads();
        const int k = t & 127;
        const float* Wk = (t < 128) ? Wki : Wks;
        const float4* Wr = (const float4*)(Wk + k * QK);
        const float4* cq = (const float4*)sQu;
        float acc2 = 0.f;
        #pragma unroll
        for (int q4 = 0; q4 < 16; ++q4) acc2 += dot4(Wr[q4], cq[q4]);
        if (t < 128) qu_i[(size_t)b * DH + k] = acc2;
        else qu_s[(size_t)b * DH + k] = acc2;
    }
}

// kin: one block per (2 b's, d). H register-resident.
// Thread layout: bb = t>>7 (which b), gg = (t&127)>>5 (row group), col4 = t&31.
// Thread owns rows r = gg + 4k (k < nr), cols 4*col4..4*col4+3 of H[b0+bb].
// __launch_bounds__(256,4): at 5 the allocator spills h4[13] (measured r1:
// VGPR 48, WRITE_SIZE 6x outputs, kin +25us).
__global__ __launch_bounds__(256, 4) void kin(
    const float* __restrict__ Hi,   // [D,B,L,DH]
    const float* __restrict__ Gi, const float* __restrict__ Gs,
    const float* __restrict__ qu_i, const float* __restrict__ qu_s,
    const float* __restrict__ Wvi, const float* __restrict__ bvi,
    float* __restrict__ qvs_w,      // [D,B,DH]
    float* __restrict__ hi_w)       // [D,B,QK]
{
    __shared__ float4 sP4[256];      // partials: c, then vagg
    __shared__ float sC2[2 * DH];    // c interleaved [j][bb]
    __shared__ float sQVi[2 * DH];   // qv_i [bb][k]
    __shared__ float sSc[128];
    __shared__ float sA[128];
    __shared__ float sVagg[2 * DH];  // [bb][col]
    __shared__ float sPA[256], sPB[256];

    const int b0 = blockIdx.x * 2;
    const int d = blockIdx.y;
    const int t = threadIdx.x;
    const int lane = t & 63, wave = t >> 6;
    const int bb = t >> 7;
    const int tb = t & 127;
    const int gg = tb >> 5;
    const int col4 = t & 31;
    const int nr = (gg < 2) ? 13 : 12;
    const float* sPf = (const float*)sP4;

    // H tile -> registers (coalesced b128)
    const float* Hbase = Hi + ((size_t)d * B + (b0 + bb)) * (L * DH);
    float4 h4[13];
    #pragma unroll
    for (int k = 0; k < 13; ++k)
        if (k < nr) h4[k] = *(const float4*)(Hbase + (gg + 4 * k) * DH + 4 * col4);

    // c partials
    {
        float4 cs = make_float4(0.f, 0.f, 0.f, 0.f);
        #pragma unroll
        for (int k = 0; k < 13; ++k)
            if (k < nr) { cs.x += h4[k].x; cs.y += h4[k].y; cs.z += h4[k].z; cs.w += h4[k].w; }
        sP4[t] = cs;
    }
    __syncthreads();
    {
        const int bbc = t >> 7, col = t & 127;
        float s = sPf[bbc * 512 + col] + sPf[bbc * 512 + 128 + col]
                + sPf[bbc * 512 + 256 + col] + sPf[bbc * 512 + 384 + col];
        sC2[col * 2 + bbc] = s * (1.0f / (float)L);
    }
    __syncthreads();

    // qv = qu + G^T c for both b's; coalesced dword G reads, LDS float2 c broadcast
    {
        const int mat = t >> 7, k = t & 127;
        const float* G = mat ? Gs : Gi;
        const float* qum = mat ? qu_s : qu_i;
        float a0 = qum[(size_t)b0 * DH + k];
        float a1 = qum[(size_t)(b0 + 1) * DH + k];
        const float2* c2 = (const float2*)sC2;
        #pragma unroll 8
        for (int j = 0; j < DH; ++j) {
            float g = G[j * DH + k];
            float2 c = c2[j];
            a0 += c.x * g;
            a1 += c.y * g;
        }
        if (mat == 0) { sQVi[k] = a0; sQVi[DH + k] = a1; }
        else {
            qvs_w[((size_t)d * B + b0) * DH + k] = a0;
            qvs_w[((size_t)d * B + b0 + 1) * DH + k] = a1;
        }
    }
    __syncthreads();

    // scores
    {
        float4 qv = ((const float4*)sQVi)[bb * 32 + col4];
        #pragma unroll
        for (int k = 0; k < 13; ++k)
            if (k < nr) {
                float p = dot4(h4[k], qv);
                p = gsum32(p);
                if (col4 == 0) sSc[bb * 64 + gg + 4 * k] = p * 0.125f;
            }
    }
    __syncthreads();
    if (wave < 2) {
        float s = (lane < L) ? sSc[wave * 64 + lane] : -3.0e38f;
        float m = wmax(s);
        float e = (lane < L) ? expf(s - m) : 0.f;
        float ssum = wsum(e);
        if (lane < L) sA[wave * 64 + lane] = e / ssum;
    }
    __syncthreads();

    // vagg partials
    {
        float4 va = make_float4(0.f, 0.f, 0.f, 0.f);
        #pragma unroll
        for (int k = 0; k < 13; ++k)
            if (k < nr) {
                float a = sA[bb * 64 + gg + 4 * k];
                va.x += a * h4[k].x; va.y += a * h4[k].y;
                va.z += a * h4[k].z; va.w += a * h4[k].w;
            }
        sP4[t] = va;
    }
    __syncthreads();
    {
        const int bbc = t >> 7, col = t & 127;
        sVagg[bbc * 128 + col] = sPf[bbc * 512 + col] + sPf[bbc * 512 + 128 + col]
                               + sPf[bbc * 512 + 256 + col] + sPf[bbc * 512 + 384 + col];
    }
    __syncthreads();

    // h_i = vagg @ Wvi + bvi for both b's (Wvi loads shared, lane-coalesced)
    {
        const int q = t & 63, kq = t >> 6;
        const int k0 = kq * 32;
        float a0 = 0.f, a1 = 0.f;
        #pragma unroll 8
        for (int i = 0; i < 32; ++i) {
            int k = k0 + i;
            float w = Wvi[k * QK + q];
            a0 += sVagg[k] * w;
            a1 += sVagg[128 + k] * w;
        }
        sPA[kq * 64 + q] = a0;
        sPB[kq * 64 + q] = a1;
    }
    __syncthreads();
    if (t < 128) {
        const int bw = t >> 6, q = t & 63;
        const float* P = bw ? sPB : sPA;
        hi_w[((size_t)d * B + b0 + bw) * QK + q] =
            bvi[q] + P[q] + P[64 + q] + P[128 + q] + P[192 + q];
    }
}

// kstat: segment sums of h per (domain, dim). 64 blocks x 32 rows.
__global__ __launch_bounds__(256) void kstat(
    const float* __restrict__ h, const int* __restrict__ dom_ids,
    float* __restrict__ gsum, float* __restrict__ gsq, float* __restrict__ gcnt)
{
    __shared__ float sS[D * DH], sQ2[D * DH], sCnt[D];
    const int t = threadIdx.x;
    const int b0 = blockIdx.x * 32;
    for (int i = t; i < D * DH; i += 256) { sS[i] = 0.f; sQ2[i] = 0.f; }
    if (t < D) sCnt[t] = 0.f;
    __syncthreads();
    const int col = t & 127, half = t >> 7;
    for (int rr = 0; rr < 16; ++rr) {
        int b = b0 + rr * 2 + half;
        float v = h[(size_t)b * DH + col];
        int dm = dom_ids[b];
        atomicAdd(&sS[dm * DH + col], v);
        atomicAdd(&sQ2[dm * DH + col], v * v);
        if (col == 0) atomicAdd(&sCnt[dm], 1.f);
    }
    __syncthreads();
    for (int i = t; i < D * DH; i += 256) {
        atomicAdd(&gsum[i], sS[i]);
        atomicAdd(&gsq[i], sQ2[i]);
    }
    if (t < D) atomicAdd(&gcnt[t], sCnt[t]);
}

// ksh: one block per b. Shared attention for all 5 domains, Hs register-resident.
__global__ __launch_bounds__(256, 4) void ksh(
    const float* __restrict__ Hs,     // [B,LS,DH]
    const float* __restrict__ qvs_w,  // [D,B,DH]
    const float* __restrict__ Wvs, const float* __restrict__ bvs,
    float* __restrict__ hs_w)         // [D,B,QK]
{
    __shared__ float4 sQV4[160];
    __shared__ float sS[D * 64];
    __shared__ float4 sVP4[1280];    // 20 KB: vagg partials / h_s partials
    __shared__ float sVA[D * DH];

    const int b = blockIdx.x;
    const int t = threadIdx.x;
    const int lane = t & 63;
    const int wave = t >> 6;
    const int g = t >> 5;
    const int col4 = t & 31;
    const int nrow = (g < 2) ? 7 : 6;
    float* sBigF = (float*)sVP4;

    const float* Hbase = Hs + (size_t)b * LS * DH;
    float4 h4[7];
    #pragma unroll
    for (int k = 0; k < 7; ++k)
        if (k < nrow) h4[k] = *(const float4*)(Hbase + (g + 8 * k) * DH + 4 * col4);
    if (t < 160) {
        int dd = t >> 5, c4 = t & 31;
        sQV4[t] = *(const float4*)(qvs_w + ((size_t)dd * B + b) * DH + 4 * c4);
    }
    __syncthreads();

    #pragma unroll
    for (int dd = 0; dd < D; ++dd) {
        float4 qv = sQV4[dd * 32 + col4];
        #pragma unroll
        for (int k = 0; k < 7; ++k)
            if (k < nrow) {
                float p = dot4(h4[k], qv);
                p = gsum32(p);
                if (col4 == 0) sS[dd * 64 + g + 8 * k] = p * 0.125f;
            }
    }
    __syncthreads();
    for (int dd = wave; dd < D; dd += 4) {
        float s = (lane < LS) ? sS[dd * 64 + lane] : -3.0e38f;
        float m = wmax(s);
        float e = (lane < LS) ? expf(s - m) : 0.f;
        float ssum = wsum(e);
        if (lane < LS) sS[dd * 64 + lane] = e / ssum;
    }
    __syncthreads();

    {
        float4 va[D];
        #pragma unroll
        for (int dd = 0; dd < D; ++dd) va[dd] = make_float4(0.f, 0.f, 0.f, 0.f);
        #pragma unroll
        for (int k = 0; k < 7; ++k)
            if (k < nrow) {
                float4 hv = h4[k];
                #pragma unroll
                for (int dd = 0; dd < D; ++dd) {
                    float a = sS[dd * 64 + g + 8 * k];
                    va[dd].x += a * hv.x; va[dd].y += a * hv.y;
                    va[dd].z += a * hv.z; va[dd].w += a * hv.w;
                }
            }
        #pragma unroll
        for (int dd = 0; dd < D; ++dd) sVP4[dd * 256 + t] = va[dd];
    }
    __syncthreads();
    for (int o = t; o < D * DH; o += 256) {
        int dd = o >> 7, col = o & 127;
        float s = 0.f;
        #pragma unroll
        for (int gg = 0; gg < 8; ++gg) s += sBigF[dd * 1024 + gg * 128 + col];
        sVA[o] = s;
    }
    __syncthreads();

    // h_s = vagg @ Wvs + bvs: 320 outputs x split-k 4 (Wvs amortized over 5 d)
    #pragma unroll
    for (int j = 0; j < 5; ++j) {
        int tau = t + j * 256;
        int kq = tau / 320;
        int o = tau - kq * 320;
        int dd = o >> 6, q = o & 63;
        float acc = 0.f;
        const int k0 = kq * 32;
        #pragma unroll 8
        for (int i = 0; i < 32; ++i) {
            int k = k0 + i;
            acc += sVA[dd * 128 + k] * Wvs[k * QK + q];
        }
        sBigF[tau] = acc;
    }
    __syncthreads();
    for (int o = t; o < D * QK; o += 256) {
        int dd = o >> 6, q = o & 63;
        hs_w[((size_t)dd * B + b) * QK + q] =
            bvs[q] + sBigF[o] + sBigF[o + 320] + sBigF[o + 640] + sBigF[o + 960];
    }
}

// kfin: one block per b. Loss, z, gb, AdaNorm epilogue.
__global__ __launch_bounds__(256) void kfin(
    const float* __restrict__ h, const int* __restrict__ dom_ids,
    const float* __restrict__ hi_w, const float* __restrict__ hs_w,
    const float* __restrict__ Wf, const float* __restrict__ bf,
    const float* __restrict__ Wgb, const float* __restrict__ bgb,
    const float* __restrict__ gsum, const float* __restrict__ gsq,
    const float* __restrict__ gcnt,
    float* __restrict__ out, float* __restrict__ loss_out)
{
    __shared__ float sHI[D * QK], sHS[D * QK];
    __shared__ float sInv[16], sSim[32], sZ[QK], sPartZ[256], sGB[256];

    const int b = blockIdx.x;
    const int t = threadIdx.x;
    const int lane = t & 63;
    const int wave = t >> 6;
    const int dm = dom_ids[b];

    if (t < 80) {
        int dd = t >> 4, q4 = t & 15;
        ((float4*)sHI)[t] = *(const float4*)(hi_w + ((size_t)dd * B + b) * QK + 4 * q4);
        ((float4*)sHS)[t] = *(const float4*)(hs_w + ((size_t)dd * B + b) * QK + 4 * q4);
    }
    __syncthreads();

    for (int v = wave; v < 2 * D; v += 4) {
        float x = (v < D) ? sHI[v * QK + lane] : sHS[(v - D) * QK + lane];
        float ss = wsum(x * x);
        if (lane == 0) sInv[v] = 1.0f / fmaxf(sqrtf(ss), 1e-12f);
    }
    __syncthreads();
    for (int p = wave; p < 30; p += 4) {
        float s;
        if (p < 25) {
            int dd = p / 5, e = p - dd * 5;
            s = wsum(sHI[dd * QK + lane] * sHI[e * QK + lane] * sInv[dd] * sInv[e]);
        } else {
            int dd = p - 25;
            s = wsum(sHI[dd * QK + lane] * sHS[dd * QK + lane] * sInv[dd] * sInv[D + dd]);
        }
        if (lane == 0) sSim[p] = s;
    }
    __syncthreads();
    if (t == 0) {
        float tot = 0.f;
        #pragma unroll
        for (int dd = 0; dd < D; ++dd) {
            float den = 0.f;
            #pragma unroll
            for (int e = 0; e < D; ++e) den += expf(sSim[dd * 5 + e]);
            tot += logf(expf(sSim[25 + dd]) / (den + 1e-8f) + 1e-8f);
        }
        atomicAdd(loss_out, -tot / (float)(B * D));
    }

    // z = [h_i[dm], h_s[dm]] @ Wf + bf
    {
        const int kq = wave, q = lane;
        float acc = 0.f;
        const int k0 = kq * 32;
        #pragma unroll 8
        for (int i = 0; i < 32; ++i) {
            int k = k0 + i;
            float x = (k < QK) ? sHI[dm * QK + k] : sHS[dm * QK + (k - QK)];
            acc += x * Wf[k * CD + q];
        }
        sPartZ[t] = acc;
    }
    __syncthreads();
    if (t < QK) sZ[t] = bf[t] + sPartZ[t] + sPartZ[64 + t] + sPartZ[128 + t] + sPartZ[192 + t];
    __syncthreads();

    {
        float acc = bgb[t];
        #pragma unroll 8
        for (int k = 0; k < CD; ++k) acc += sZ[k] * Wgb[k * (2 * DH) + t];
        sGB[t] = acc;
    }
    __syncthreads();

    if (t < DH) {
        float c = fmaxf(gcnt[dm], 1.0f);
        float mu = gsum[dm * DH + t] / c;
        float va = gsq[dm * DH + t] / c - mu * mu;
        float hv = h[(size_t)b * DH + t];
        float hn = (hv - mu) / sqrtf(va + EPS);
        out[(size_t)b * DH + t] = sGB[t] * hn + sGB[DH + t] + hv;
    }
}

extern "C" void kernel_launch(void* const* d_in, const int* in_sizes, int n_in,
                              void* d_out, int out_size, void* d_ws, size_t ws_size,
                              hipStream_t stream)
{
    (void)in_sizes; (void)n_in; (void)out_size; (void)ws_size;
    const float* u   = (const float*)d_in[0];
    const float* Hi  = (const float*)d_in[1];
    const float* Hs  = (const float*)d_in[2];
    const float* h   = (const float*)d_in[3];
    const int*   dom = (const int*)d_in[4];
    const float* Wq  = (const float*)d_in[5];
    const float* bq  = (const float*)d_in[6];
    const float* Wki = (const float*)d_in[7];
    // d_in[8] = bki: unused (softmax shift-invariance)
    const float* Wvi = (const float*)d_in[9];
    const float* bvi = (const float*)d_in[10];
    const float* Wks = (const float*)d_in[11];
    // d_in[12] = bks: unused (softmax shift-invariance)
    const float* Wvs = (const float*)d_in[13];
    const float* bvs = (const float*)d_in[14];
    const float* Wf  = (const float*)d_in[15];
    const float* bf  = (const float*)d_in[16];
    const float* Wgb = (const float*)d_in[17];
    const float* bgb = (const float*)d_in[18];

    float* out = (float*)d_out;
    float* loss_out = out + (size_t)B * DH;

    float* ws = (float*)d_ws;
    float* Gi    = ws;                                // DH*DH
    float* Gs    = Gi + DH * DH;                      // DH*DH
    float* qu_i  = Gs + DH * DH;                      // B*DH
    float* qu_s  = qu_i + (size_t)B * DH;             // B*DH
    float* qvs_w = qu_s + (size_t)B * DH;             // D*B*DH
    float* hi_w  = qvs_w + (size_t)D * B * DH;        // D*B*QK
    float* hs_w  = hi_w + (size_t)D * B * QK;         // D*B*QK
    float* gsum  = hs_w + (size_t)D * B * QK;         // D*DH
    float* gsq   = gsum + D * DH;                     // D*DH
    float* gcnt  = gsq + D * DH;                      // 8

    hipMemsetAsync(gsum, 0, (size_t)(2 * D * DH + 8) * sizeof(float), stream);
    hipMemsetAsync(loss_out, 0, sizeof(float), stream);

    hipLaunchKernelGGL(ksetup, dim3(DH + B), dim3(256), 0, stream,
                       u, Wq, bq, Wki, Wks, Gi, Gs, qu_i, qu_s);
    hipLaunchKernelGGL(kstat, dim3(B / 32), dim3(256), 0, stream, h, dom, gsum, gsq, gcnt);
    hipLaunchKernelGGL(kin, dim3(B / 2, D), dim3(256), 0, stream,
                       Hi, Gi, Gs, qu_i, qu_s, Wvi, bvi, qvs_w, hi_w);
    hipLaunchKernelGGL(ksh, dim3(B), dim3(256), 0, stream, Hs, qvs_w, Wvs, bvs, hs_w);
    hipLaunchKernelGGL(kfin, dim3(B), dim3(256), 0, stream,
                       h, dom, hi_w, hs_w, Wf, bf, Wgb, bgb, gsum, gsq, gcnt, out, loss_out);
}